// Round 8
// baseline (6200.841 us; speedup 1.0000x reference)
//
#include <hip/hip_runtime.h>
#include <float.h>

#define V 50000
#define E 100
#define H 512
#define T 200
#define B 256
#define NC 5
#define K0 640            // layer0 concat-K: 128 (emb pad) + 512
#define K1 1024           // layer1 concat-K: 512 + 512
#define NH (B * H)        // 131072
#define NW0 (2048 * K0)
#define NW1 (2048 * K1)
#define LOSC 4096.0f      // lo-plane scale (2^12) keeps lo out of fp16 denormals
#define ILOSC (1.0f / 4096.0f)
#define NBLK 256          // 1 block / CU
#define HSLOT (NH * 2)    // halves per h slot (hi+lo interleaved records)

typedef _Float16 half8 __attribute__((ext_vector_type(8)));
typedef float floatx4 __attribute__((ext_vector_type(4)));
typedef unsigned long long u64;

// ---------------- activations ----------------
__device__ __forceinline__ float fsig(float x)  { return 1.f / (1.f + __expf(-x)); }
__device__ __forceinline__ float ftanh(float x) { return 1.f - 2.f / (__expf(2.f * x) + 1.f); }

// ---------------- sc1 store (coherence point). h WRITES only. ----------------
// h READS are plain: at kernel start L2 is invalidated; within a dispatch each
// h line is plain-read only AFTER its sc1 write (ordered by the mid-kernel
// barrier) and never before -> no stale L2 copy can be observed.
__device__ __forceinline__ void st_u64_cc(void* p, u64 v) {
    __hip_atomic_store((u64*)p, v, __ATOMIC_RELAXED, __HIP_MEMORY_SCOPE_AGENT);
}

// ---------------- workspace map ----------------
// h layout (hi/lo interleaved): h[slot][b][H/8] records of 16 halves:
//   halves 0..7 = hi of 8-j chunk, 8..15 = lo.  (r3/r5 proven layout)
struct WS {
    _Float16 *W0h, *W0l, *W1h, *W1l;   // [2048][K] split planes, c = j*4+g
    _Float16 *h0, *h1;                 // [2 slots][B][H/8][16] interleaved
    float *c0, *c1, *hmax;             // [B][H]
    int *last;                         // [B]
    unsigned *arr;                     // [NBLK] arrival words (sc1)
    unsigned *gen;                     // generation word (sc1, own line)
};
__device__ __host__ inline WS wsmap(char* p) {
    WS w;
    w.W0h = (_Float16*)p;  p += (size_t)NW0 * 2;
    w.W0l = (_Float16*)p;  p += (size_t)NW0 * 2;
    w.W1h = (_Float16*)p;  p += (size_t)NW1 * 2;
    w.W1l = (_Float16*)p;  p += (size_t)NW1 * 2;
    w.h0  = (_Float16*)p;  p += (size_t)2 * HSLOT * 2;   // 1 MiB
    w.h1  = (_Float16*)p;  p += (size_t)2 * HSLOT * 2;   // 1 MiB
    w.c0   = (float*)p;    p += (size_t)NH * 4;
    w.c1   = (float*)p;    p += (size_t)NH * 4;
    w.hmax = (float*)p;    p += (size_t)NH * 4;
    w.last = (int*)p;      p += (size_t)B * 4;
    w.arr  = (unsigned*)p;                 // +0 .. +1023
    w.gen  = (unsigned*)(p + 1024);        // own 128B line
    return w;
}

// ---------------- prep: split weights into fp16 hi/lo catenated layout ----------------
__global__ void k_prep(const float* __restrict__ Wih0, const float* __restrict__ Whh0,
                       const float* __restrict__ Wih1, const float* __restrict__ Whh1,
                       char* wsraw) {
    WS w = wsmap(wsraw);
    int idx = blockIdx.x * 256 + threadIdx.x;
    if (idx < NW0) {
        int c = idx / K0, k = idx - c * K0;
        int jx = c >> 2, g = c & 3, row = g * H + jx;
        float v = 0.f;
        if (k < 128) { if (k < E) v = Wih0[(size_t)row * E + k]; }
        else           v = Whh0[(size_t)row * H + (k - 128)];
        _Float16 hh = (_Float16)v;
        w.W0h[idx] = hh;
        w.W0l[idx] = (_Float16)((v - (float)hh) * LOSC);
    } else if (idx < NW0 + NW1) {
        int i2 = idx - NW0;
        int c = i2 / K1, k = i2 - c * K1;
        int jx = c >> 2, g = c & 3, row = g * H + jx;
        float v = (k < H) ? Wih1[(size_t)row * H + k]
                          : Whh1[(size_t)row * H + (k - H)];
        _Float16 hh = (_Float16)v;
        w.W1h[i2] = hh;
        w.W1l[i2] = (_Float16)((v - (float)hh) * LOSC);
    }
}

// ---------------- init: zero h planes & c, hmax=-FLT_MAX, last[b], sync words ----
__global__ void k_init(const int* __restrict__ X, char* wsraw) {
    WS w = wsmap(wsraw);
    int i = blockIdx.x * 256 + threadIdx.x;
    if (i < 524288)                      ((unsigned*)w.h0)[i] = 0u;          // h0,h1 = 2 MiB
    else if (i < 524288 + 262144)        ((unsigned*)w.c0)[i - 524288] = 0u; // c0,c1
    else if (i < 524288 + 262144 + NH)   w.hmax[i - 786432] = -FLT_MAX;
    if (i < 512) w.arr[i] = 0u;          // arr + gen page
    if (i < B) {
        int l = -1;
        const int* xr = X + i * T;
        for (int t = 0; t < T; ++t) if (xr[t] != V) l = t;
        w.last[i] = l;
    }
}

// ---------------- prefetch of a phase's h-independent fragments ----------------
template <int LAYER>
struct Pref { half8 Ah[4], Al[4], Bh[4], Bl[4]; };

template <int LAYER>
__device__ __forceinline__ void prefetch0(
    int t, const int* __restrict__ X, const float* __restrict__ emb,
    const _Float16* __restrict__ Wh, const _Float16* __restrict__ Wl,
    int c0g, int b0gl, int m, int qq, int wq, Pref<LAYER>& P)
{
    const int KT = LAYER ? K1 : K0;
    const int ko = wq * 32 + qq * 8;              // kb = wq
#pragma unroll
    for (int cs = 0; cs < 4; ++cs) {
        const size_t ro = (size_t)(c0g + cs * 16 + m) * KT + ko;
        P.Ah[cs] = *(const half8*)(Wh + ro);
        P.Al[cs] = *(const half8*)(Wl + ro);
    }
    if (LAYER == 0) {                             // kb = wq < 4 -> emb, convert now
#pragma unroll
        for (int bs = 0; bs < 4; ++bs) {
            int er = X[(b0gl + bs * 16 + m) * T + t];
            const float* p = emb + (size_t)er * E;
            float4 fa = make_float4(0.f,0.f,0.f,0.f), fb = fa;
            if (ko <= 96) fa = *(const float4*)(p + ko);
            if (ko <= 92) fb = *(const float4*)(p + ko + 4);
            float e[8] = {fa.x,fa.y,fa.z,fa.w, fb.x,fb.y,fb.z,fb.w};
#pragma unroll
            for (int u = 0; u < 8; ++u) {
                _Float16 hv = (_Float16)e[u];
                P.Bh[bs][u] = hv;
                P.Bl[bs][u] = (_Float16)((e[u] - (float)hv) * LOSC);
            }
        }
    }
}

// ---------------- K-quarter MFMA loop (per wave); h via PLAIN record loads ------
template <int LAYER>
__device__ __forceinline__ void run_mm(
    const Pref<LAYER>& P,
    const _Float16* __restrict__ Wh, const _Float16* __restrict__ Wl,
    const _Float16* __restrict__ x0, const _Float16* __restrict__ x1,
    int c0g, int b0gl, int m, int qq, int wq,
    floatx4 (&acc0)[16], floatx4 (&acc1)[16])
{
    const int KT  = LAYER ? K1 : K0;
    const int NKB = LAYER ? 8 : 5;    // k-blocks of 32 per wave (kb = wq + 4*i)
    half8 A_h[2][4], A_l[2][4], B_h[2][4], B_l[2][4];

    auto ldA = [&](int kb, int buf) {
        const int ko = kb * 32 + qq * 8;
#pragma unroll
        for (int cs = 0; cs < 4; ++cs) {
            const size_t ro = (size_t)(c0g + cs * 16 + m) * KT + ko;
            A_h[buf][cs] = *(const half8*)(Wh + ro);
            A_l[buf][cs] = *(const half8*)(Wl + ro);
        }
    };
    auto ldB = [&](int kb, int buf) {             // h-records, plain (L2-dedup'd)
        const int ko = kb * 32 + qq * 8;
        const _Float16* sx; int kk;
        if (LAYER == 0)   { sx = x0; kk = ko - 128; }
        else if (kb < 16) { sx = x0; kk = ko; }
        else              { sx = x1; kk = ko - 512; }
        const int ch = kk >> 3;
#pragma unroll
        for (int bs = 0; bs < 4; ++bs) {
            const _Float16* bp = sx + ((size_t)(b0gl + bs * 16 + m) * (H/8) + ch) * 16;
            B_h[buf][bs] = *(const half8*)(bp);
            B_l[buf][bs] = *(const half8*)(bp + 8);
        }
    };

    // buf0: A (and layer0 emb-B) from prefetch; layer1 B loaded now (needs fresh h)
#pragma unroll
    for (int cs = 0; cs < 4; ++cs) { A_h[0][cs] = P.Ah[cs]; A_l[0][cs] = P.Al[cs]; }
    if (LAYER == 0) {
#pragma unroll
        for (int bs = 0; bs < 4; ++bs) { B_h[0][bs] = P.Bh[bs]; B_l[0][bs] = P.Bl[bs]; }
    } else {
        ldB(wq, 0);
    }

#pragma unroll
    for (int i = 0; i < NKB; ++i) {
        const int cur = i & 1;
        if (i + 1 < NKB) { ldA(wq + 4 * (i + 1), cur ^ 1); ldB(wq + 4 * (i + 1), cur ^ 1); }
#pragma unroll
        for (int cs = 0; cs < 4; ++cs)
#pragma unroll
            for (int bs = 0; bs < 4; ++bs) {
                const int ti = cs * 4 + bs;
                acc0[ti] = __builtin_amdgcn_mfma_f32_16x16x32_f16(A_h[cur][cs], B_h[cur][bs], acc0[ti], 0, 0, 0);
                acc1[ti] = __builtin_amdgcn_mfma_f32_16x16x32_f16(A_h[cur][cs], B_l[cur][bs], acc1[ti], 0, 0, 0);
                acc1[ti] = __builtin_amdgcn_mfma_f32_16x16x32_f16(A_l[cur][cs], B_h[cur][bs], acc1[ti], 0, 0, 0);
            }
    }
}

// ---------------- two-step fused dispatch: phase A (t0), barrier, phase B (t0+1) --
// Phase B re-reads the SAME weight rows as phase A: clean L2 lines survive the
// intra-kernel barrier -> weight fetch amortized over 2 steps. c/hmax ride in
// registers across both phases. h writes sc1 (cross-XCD visible at barrier).
__global__ __launch_bounds__(256, 1) void k_step2(
    int t0, unsigned tgt, const int* __restrict__ X, const float* __restrict__ emb,
    const float* __restrict__ b0, const float* __restrict__ b1,
    char* __restrict__ wsraw)
{
    extern __shared__ float red[];    // [4 waves][64 b][68]  (c-minor, +4 pad)

    const int tid = threadIdx.x, lane = tid & 63, wq = tid >> 6;
    const int m = lane & 15, qq = lane >> 4;
    const int bid = blockIdx.x;
    const int xcd = bid & 7, slot = bid >> 3;
    const int layer = slot >> 4, bblk = (slot >> 2) & 3, chi = slot & 3;
    const int cblk = chi * 8 + xcd;
    const int c0g = cblk * 64, b0gl = bblk * 64, j0g = cblk * 16;

    WS w = wsmap(wsraw);

    // ---- epilogue lane mapping: lane owns (1 b) x (4 contiguous j) ----
    const int b16 = lane & 15, jq = lane >> 4;
    const int bl_e = wq * 16 + b16;
    const int bg_e = b0gl + bl_e;
    const int jb = jq * 4;
    const int ch_e  = (j0g + jb) >> 3;            // h record chunk
    const int hsel  = (jb >> 2) & 1;              // quad within chunk
    const float* bias = layer ? b1 : b0;
    float bv[4][4];
#pragma unroll
    for (int g = 0; g < 4; ++g)
#pragma unroll
        for (int u = 0; u < 4; ++u)
            bv[g][u] = bias[g * H + j0g + jb + u];

    // ---- register-resident state across both phases ----
    float* cst = layer ? w.c1 : w.c0;
    float4 cv = *(const float4*)(cst + (size_t)bg_e * H + j0g + jb);
    float creg[4] = {cv.x, cv.y, cv.z, cv.w};
    float4 hv = *(const float4*)(w.hmax + (size_t)bg_e * H + j0g + jb);
    float hmreg[4] = {hv.x, hv.y, hv.z, hv.w};
    const int lastb = w.last[bg_e];

    Pref<0> P0; Pref<1> P1;
    if (layer == 0) { if (t0 < T) prefetch0<0>(t0, X, emb, w.W0h, w.W0l, c0g, b0gl, m, qq, wq, P0); }
    else            prefetch0<1>(0, X, emb, w.W1h, w.W1l, c0g, b0gl, m, qq, wq, P1);

    auto do_phase = [&](int t) {
        const int tt = t - 1;
        const bool act = layer ? (t >= 1 && t <= T) : (t < T);
        if (!act) return;
        floatx4 acc0[16], acc1[16];
#pragma unroll
        for (int i = 0; i < 16; ++i) {
            floatx4 z = {0.f, 0.f, 0.f, 0.f};
            acc0[i] = z; acc1[i] = z;
        }

        if (layer == 0)
            run_mm<0>(P0, w.W0h, w.W0l,
                      w.h0 + (size_t)((t + 1) & 1) * HSLOT, nullptr,
                      c0g, b0gl, m, qq, wq, acc0, acc1);
        else
            run_mm<1>(P1, w.W1h, w.W1l,
                      w.h0 + (size_t)(tt & 1) * HSLOT,
                      w.h1 + (size_t)((tt + 1) & 1) * HSLOT,
                      c0g, b0gl, m, qq, wq, acc0, acc1);

        // ---- fold lo-acc, dump k-quarter partials ----
#pragma unroll
        for (int cs = 0; cs < 4; ++cs)
#pragma unroll
            for (int bs = 0; bs < 4; ++bs) {
                floatx4 v = acc0[cs * 4 + bs] + acc1[cs * 4 + bs] * ILOSC;
                const int bl = bs * 16 + m, cl = cs * 16 + qq * 4;
                *(floatx4*)&red[((wq * 64 + bl) * 68 + cl)] = v;
            }
        __syncthreads();

        // ---- reduce 4 quarters + epilogue ----
        _Float16* o = (layer ? w.h1 + (size_t)(tt & 1) * HSLOT
                             : w.h0 + (size_t)(t  & 1) * HSLOT);
        float hn4[4];
#pragma unroll
        for (int u = 0; u < 4; ++u) {
            floatx4 g = *(floatx4*)&red[((0 * 64 + bl_e) * 68 + (jb + u) * 4)];
#pragma unroll
            for (int q2 = 1; q2 < 4; ++q2)
                g += *(floatx4*)&red[((q2 * 64 + bl_e) * 68 + (jb + u) * 4)];
            float ig = fsig (g.x + bv[0][u]);
            float fg = fsig (g.y + bv[1][u]);
            float gg = ftanh(g.z + bv[2][u]);
            float og = fsig (g.w + bv[3][u]);
            float cn = fg * creg[u] + ig * gg;
            float hn = og * ftanh(cn);
            creg[u] = cn;
            hn4[u] = hn;
        }
        if (layer == 1 && tt <= lastb) {
#pragma unroll
            for (int u = 0; u < 4; ++u) hmreg[u] = fmaxf(hmreg[u], hn4[u]);
        }
        union { _Float16 h[4]; u64 uu; } ph, pl;
#pragma unroll
        for (int u = 0; u < 4; ++u) {
            _Float16 hh = (_Float16)hn4[u];
            ph.h[u] = hh;
            pl.h[u] = (_Float16)((hn4[u] - (float)hh) * LOSC);
        }
        _Float16* rec = o + ((size_t)bg_e * (H/8) + ch_e) * 16 + hsel * 4;
        st_u64_cc(rec,     ph.uu);            // hi quad
        st_u64_cc(rec + 8, pl.uu);            // lo quad (same 32B record)
    };

    // ================= phase A =================
    do_phase(t0);

    // ---- barrier arrive: drain sc1 h-stores, publish arrival ----
    asm volatile("s_waitcnt vmcnt(0)" ::: "memory");
    __syncthreads();
    if (tid == 0)
        __hip_atomic_store(&w.arr[bid], tgt, __ATOMIC_RELAXED, __HIP_MEMORY_SCOPE_AGENT);

    // ---- barrier-overlapped prefetch for phase B ----
    const int t1 = t0 + 1;
    if (layer == 0) { if (t1 < T) prefetch0<0>(t1, X, emb, w.W0h, w.W0l, c0g, b0gl, m, qq, wq, P0); }
    else            prefetch0<1>(0, X, emb, w.W1h, w.W1l, c0g, b0gl, m, qq, wq, P1);

    // ---- barrier wait: block 0 aggregates, others poll one word (r3-proven) ----
    if (bid == 0) {
        if (tid < 64) {
            for (;;) {
                unsigned f0 = __hip_atomic_load(&w.arr[tid],       __ATOMIC_RELAXED, __HIP_MEMORY_SCOPE_AGENT);
                unsigned f1 = __hip_atomic_load(&w.arr[tid + 64],  __ATOMIC_RELAXED, __HIP_MEMORY_SCOPE_AGENT);
                unsigned f2 = __hip_atomic_load(&w.arr[tid + 128], __ATOMIC_RELAXED, __HIP_MEMORY_SCOPE_AGENT);
                unsigned f3 = __hip_atomic_load(&w.arr[tid + 192], __ATOMIC_RELAXED, __HIP_MEMORY_SCOPE_AGENT);
                bool ok = (f0 >= tgt) & (f1 >= tgt) & (f2 >= tgt) & (f3 >= tgt);
                if (__all(ok)) break;
                __builtin_amdgcn_s_sleep(2);
            }
            if (tid == 0)
                __hip_atomic_store(w.gen, tgt, __ATOMIC_RELAXED, __HIP_MEMORY_SCOPE_AGENT);
        }
    } else {
        if (tid == 0) {
            while (__hip_atomic_load(w.gen, __ATOMIC_RELAXED, __HIP_MEMORY_SCOPE_AGENT) < tgt)
                __builtin_amdgcn_s_sleep(4);
        }
    }
    __syncthreads();
    asm volatile("" ::: "memory");

    // ================= phase B =================
    do_phase(t1);

    // ---- spill register state (plain; kernel-end writeback publishes) ----
    *(float4*)(cst + (size_t)bg_e * H + j0g + jb) = make_float4(creg[0], creg[1], creg[2], creg[3]);
    if (layer == 1)
        *(float4*)(w.hmax + (size_t)bg_e * H + j0g + jb) = make_float4(hmreg[0], hmreg[1], hmreg[2], hmreg[3]);
}

// ---------------- final: logits ----------------
__global__ __launch_bounds__(64) void k_out(const float* __restrict__ hmax,
                                            const float* __restrict__ Wout,
                                            const float* __restrict__ bout,
                                            float* __restrict__ out) {
    const int b = blockIdx.x * 64 + threadIdx.x;
    float a[NC] = {0.f, 0.f, 0.f, 0.f, 0.f};
    const float* hm = hmax + (size_t)b * H;
    for (int j = 0; j < H; ++j) {
        float hv = hm[j];
#pragma unroll
        for (int cls = 0; cls < NC; ++cls)
            a[cls] = fmaf(hv, Wout[cls * H + j], a[cls]);
    }
#pragma unroll
    for (int cls = 0; cls < NC; ++cls)
        out[b * NC + cls] = a[cls] + bout[cls];
}

// ---------------- launch ----------------
extern "C" void kernel_launch(void* const* d_in, const int* in_sizes, int n_in,
                              void* d_out, int out_size, void* d_ws, size_t ws_size,
                              hipStream_t stream) {
    const int*   X    = (const int*)  d_in[0];
    const float* emb  = (const float*)d_in[1];
    const float* Wih0 = (const float*)d_in[2];
    const float* Whh0 = (const float*)d_in[3];
    const float* b0   = (const float*)d_in[4];
    const float* Wih1 = (const float*)d_in[5];
    const float* Whh1 = (const float*)d_in[6];
    const float* b1   = (const float*)d_in[7];
    const float* Wout = (const float*)d_in[8];
    const float* bout = (const float*)d_in[9];
    float* out = (float*)d_out;
    char* ws = (char*)d_ws;
    WS w = wsmap(ws);

    k_prep<<<(NW0 + NW1 + 255) / 256, 256, 0, stream>>>(Wih0, Whh0, Wih1, Whh1, ws);
    k_init<<<3584, 256, 0, stream>>>(X, ws);

    // Dispatch d covers t = 2d (phase A) and t = 2d+1 (phase B); d = 0..100
    // covers t = 0..201 (guards deactivate t=201). One grid barrier per dispatch.
    const unsigned smem = (unsigned)(4 * 64 * 68 * sizeof(float));  // 69,632 B
    for (int d = 0; d <= 100; ++d) {
        int t0 = 2 * d;
        unsigned tgt = (unsigned)(d + 1);
        void* args[] = {(void*)&t0, (void*)&tgt, (void*)&X, (void*)&emb,
                        (void*)&b0, (void*)&b1, (void*)&ws};
        hipError_t e = hipLaunchCooperativeKernel((const void*)k_step2, dim3(NBLK), dim3(256),
                                                  args, smem, stream);
        if (e != hipSuccess) {
            // 256 blocks at 1/CU with nothing else resident: co-residency holds.
            k_step2<<<NBLK, 256, smem, stream>>>(t0, tgt, X, emb, b0, b1, ws);
        }
    }

    k_out<<<4, 64, 0, stream>>>(w.hmax, Wout, bout, out);
}

// Round 9
// 6133.474 us; speedup vs baseline: 1.0110x; 1.0110x over previous
//
#include <hip/hip_runtime.h>
#include <float.h>

#define V 50000
#define E 100
#define H 512
#define T 200
#define B 256
#define NC 5
#define K0 640            // layer0 concat-K: 128 (emb pad) + 512
#define K1 1024           // layer1 concat-K: 512 + 512
#define NH (B * H)        // 131072
#define NW0 (2048 * K0)
#define NW1 (2048 * K1)
#define LOSC 4096.0f      // lo-plane scale (2^12) keeps lo out of fp16 denormals
#define ILOSC (1.0f / 4096.0f)
#define NBLK 256          // 1 block / CU (high reg use -> 1 wave/SIMD)
#define HSLOT (NH * 2)    // halves per h slot (hi+lo interleaved records)

typedef _Float16 half8 __attribute__((ext_vector_type(8)));
typedef float floatx4 __attribute__((ext_vector_type(4)));
typedef unsigned long long u64;

// ---------------- activations ----------------
__device__ __forceinline__ float fsig(float x)  { return 1.f / (1.f + __expf(-x)); }
__device__ __forceinline__ float ftanh(float x) { return 1.f - 2.f / (__expf(2.f * x) + 1.f); }

// ---------------- coherence-point helpers (agent-scope relaxed = sc1) ----------
// All h traffic is sc1 (MALL-served, cross-XCD coherent). No fences/invalidates
// anywhere in the kernel -> emb/X/bias stay L2-cached; weights live in REGISTERS.
__device__ __forceinline__ half8 ld_h8_cc(const _Float16* p) {
    u64 a = __hip_atomic_load((const u64*)p,       __ATOMIC_RELAXED, __HIP_MEMORY_SCOPE_AGENT);
    u64 b = __hip_atomic_load(((const u64*)p) + 1, __ATOMIC_RELAXED, __HIP_MEMORY_SCOPE_AGENT);
    union { u64 u[2]; half8 h; } x; x.u[0] = a; x.u[1] = b; return x.h;
}
__device__ __forceinline__ void st_u64_cc(void* p, u64 v) {
    __hip_atomic_store((u64*)p, v, __ATOMIC_RELAXED, __HIP_MEMORY_SCOPE_AGENT);
}

// ---------------- workspace map ----------------
// h layout (hi/lo interleaved): h[slot][b][H/8] records of 16 halves:
//   halves 0..7 = hi of 8-j chunk, 8..15 = lo.  (r3/r5/r8 proven layout)
struct WS {
    _Float16 *W0h, *W0l, *W1h, *W1l;   // [2048][K] split planes, c = j*4+g
    _Float16 *h0, *h1;                 // [2 slots][B][H/8][16] interleaved
    float *c0, *c1, *hmax;             // c0/c1 unused (register-resident)
    int *last;                         // [B]
    unsigned *arr;                     // [NBLK] arrival words (sc1)
    unsigned *gen;                     // generation word (sc1, own line)
};
__device__ __host__ inline WS wsmap(char* p) {
    WS w;
    w.W0h = (_Float16*)p;  p += (size_t)NW0 * 2;
    w.W0l = (_Float16*)p;  p += (size_t)NW0 * 2;
    w.W1h = (_Float16*)p;  p += (size_t)NW1 * 2;
    w.W1l = (_Float16*)p;  p += (size_t)NW1 * 2;
    w.h0  = (_Float16*)p;  p += (size_t)2 * HSLOT * 2;   // 1 MiB
    w.h1  = (_Float16*)p;  p += (size_t)2 * HSLOT * 2;   // 1 MiB
    w.c0   = (float*)p;    p += (size_t)NH * 4;
    w.c1   = (float*)p;    p += (size_t)NH * 4;
    w.hmax = (float*)p;    p += (size_t)NH * 4;
    w.last = (int*)p;      p += (size_t)B * 4;
    w.arr  = (unsigned*)p;                 // +0 .. +1023
    w.gen  = (unsigned*)(p + 1024);        // own 128B line
    return w;
}

// ---------------- prep: split weights into fp16 hi/lo catenated layout ----------------
__global__ void k_prep(const float* __restrict__ Wih0, const float* __restrict__ Whh0,
                       const float* __restrict__ Wih1, const float* __restrict__ Whh1,
                       char* wsraw) {
    WS w = wsmap(wsraw);
    int idx = blockIdx.x * 256 + threadIdx.x;
    if (idx < NW0) {
        int c = idx / K0, k = idx - c * K0;
        int jx = c >> 2, g = c & 3, row = g * H + jx;
        float v = 0.f;
        if (k < 128) { if (k < E) v = Wih0[(size_t)row * E + k]; }
        else           v = Whh0[(size_t)row * H + (k - 128)];
        _Float16 hh = (_Float16)v;
        w.W0h[idx] = hh;
        w.W0l[idx] = (_Float16)((v - (float)hh) * LOSC);
    } else if (idx < NW0 + NW1) {
        int i2 = idx - NW0;
        int c = i2 / K1, k = i2 - c * K1;
        int jx = c >> 2, g = c & 3, row = g * H + jx;
        float v = (k < H) ? Wih1[(size_t)row * H + k]
                          : Whh1[(size_t)row * H + (k - H)];
        _Float16 hh = (_Float16)v;
        w.W1h[i2] = hh;
        w.W1l[i2] = (_Float16)((v - (float)hh) * LOSC);
    }
}

// ---------------- init: zero h planes, last[b], barrier words ----------------
__global__ void k_init(const int* __restrict__ X, char* wsraw) {
    WS w = wsmap(wsraw);
    int i = blockIdx.x * 256 + threadIdx.x;
    if (i < 524288) ((unsigned*)w.h0)[i] = 0u;   // h0,h1 contiguous = 2 MiB
    if (i < 512)    w.arr[i] = 0u;               // arr + gen page
    if (i < B) {
        int l = -1;
        const int* xr = X + i * T;
        for (int t = 0; t < T; ++t) if (xr[t] != V) l = t;
        w.last[i] = l;
    }
}

// ---------------- persistent kernel: weights in registers, 1 barrier/step ------
// 256 blocks = 64 cblk (32 c-rows, 8 j) x 4 bblk (64 b); each block runs BOTH
// layers each iteration: L0(t) then L1(t-1) (both consume only last-barrier
// data). Weight regs/thread: L0 5kb x 2cs x 2pl + L1 8kb x 2cs x 2pl = 52 half8
// = 208 VGPR/AGPR (unified file, launch_bounds(256,1) -> ~512 budget).
__global__ __launch_bounds__(256, 1) void k_lstm(
    const int* __restrict__ X, const float* __restrict__ emb,
    const float* __restrict__ b0, const float* __restrict__ b1,
    char* __restrict__ wsraw)
{
    __shared__ float red[4 * 64 * 36];   // [wave][64 b][36] (c-minor, +4 pad)

    const int tid = threadIdx.x, lane = tid & 63, wq = tid >> 6;
    const int m = lane & 15, qq = lane >> 4;
    const int bid = blockIdx.x;
    const int cblk = bid & 63, bblk = bid >> 6;
    const int c0g = cblk * 32, b0gl = bblk * 64, j0g = cblk * 8;

    WS w = wsmap(wsraw);

    // ---- preload this thread's weight fragments into registers (once) ----
    half8 W0hr[5][2], W0lr[5][2], W1hr[8][2], W1lr[8][2];
#pragma unroll
    for (int i = 0; i < 5; ++i)
#pragma unroll
        for (int cs = 0; cs < 2; ++cs) {
            const size_t ro = (size_t)(c0g + cs * 16 + m) * K0 + (wq + 4 * i) * 32 + qq * 8;
            W0hr[i][cs] = *(const half8*)(w.W0h + ro);
            W0lr[i][cs] = *(const half8*)(w.W0l + ro);
        }
#pragma unroll
    for (int i = 0; i < 8; ++i)
#pragma unroll
        for (int cs = 0; cs < 2; ++cs) {
            const size_t ro = (size_t)(c0g + cs * 16 + m) * K1 + (wq + 4 * i) * 32 + qq * 8;
            W1hr[i][cs] = *(const half8*)(w.W1h + ro);
            W1lr[i][cs] = *(const half8*)(w.W1l + ro);
        }

    // ---- epilogue mapping: threads 0..127, thread = (b, j-quad) ----
    const int eb = tid & 63, equad = (tid >> 6) & 1;
    const bool eact = tid < 128;
    const int bg_e = b0gl + eb;
    float c0r[4] = {0.f, 0.f, 0.f, 0.f};
    float c1r[4] = {0.f, 0.f, 0.f, 0.f};
    float hmr[4] = {-FLT_MAX, -FLT_MAX, -FLT_MAX, -FLT_MAX};
    const int lastb = w.last[bg_e];

    for (int t = 0; t <= T; ++t) {
        // ================= phase L0(t): g = W0 * [emb(x_t); h0(t-1)] =================
        if (t < T) {
            floatx4 acc0[8], acc1[8];
#pragma unroll
            for (int i = 0; i < 8; ++i) {
                floatx4 z = {0.f, 0.f, 0.f, 0.f};
                acc0[i] = z; acc1[i] = z;
            }
            half8 Bh[2][4], Bl[2][4];
            // kb = wq (<4): emb region, convert on the fly
            {
                const int ko = wq * 32 + qq * 8;
#pragma unroll
                for (int bs = 0; bs < 4; ++bs) {
                    int er = X[(b0gl + bs * 16 + m) * T + t];
                    const float* p = emb + (size_t)er * E;
                    float4 fa = make_float4(0.f,0.f,0.f,0.f), fb = fa;
                    if (ko <= 96) fa = *(const float4*)(p + ko);
                    if (ko <= 92) fb = *(const float4*)(p + ko + 4);
                    float e[8] = {fa.x,fa.y,fa.z,fa.w, fb.x,fb.y,fb.z,fb.w};
                    half8 hh, hl;
#pragma unroll
                    for (int u = 0; u < 8; ++u) {
                        _Float16 hv = (_Float16)e[u];
                        hh[u] = hv;
                        hl[u] = (_Float16)((e[u] - (float)hv) * LOSC);
                    }
                    Bh[0][bs] = hh; Bl[0][bs] = hl;
                }
            }
            const _Float16* x0 = w.h0 + (size_t)((t + 1) & 1) * HSLOT;
#pragma unroll
            for (int i = 0; i < 5; ++i) {
                const int cur = i & 1;
                if (i + 1 < 5) {
                    const int kk = (wq + 4 * (i + 1)) * 32 + qq * 8 - 128;
                    const int ch = kk >> 3;
#pragma unroll
                    for (int bs = 0; bs < 4; ++bs) {
                        const _Float16* bp = x0 + ((size_t)(b0gl + bs * 16 + m) * (H/8) + ch) * 16;
                        Bh[cur ^ 1][bs] = ld_h8_cc(bp);
                        Bl[cur ^ 1][bs] = ld_h8_cc(bp + 8);
                    }
                }
#pragma unroll
                for (int cs = 0; cs < 2; ++cs)
#pragma unroll
                    for (int bs = 0; bs < 4; ++bs) {
                        const int ti = cs * 4 + bs;
                        acc0[ti] = __builtin_amdgcn_mfma_f32_16x16x32_f16(W0hr[i][cs], Bh[cur][bs], acc0[ti], 0, 0, 0);
                        acc1[ti] = __builtin_amdgcn_mfma_f32_16x16x32_f16(W0hr[i][cs], Bl[cur][bs], acc1[ti], 0, 0, 0);
                        acc1[ti] = __builtin_amdgcn_mfma_f32_16x16x32_f16(W0lr[i][cs], Bh[cur][bs], acc1[ti], 0, 0, 0);
                    }
            }
#pragma unroll
            for (int cs = 0; cs < 2; ++cs)
#pragma unroll
                for (int bs = 0; bs < 4; ++bs) {
                    floatx4 v = acc0[cs * 4 + bs] + acc1[cs * 4 + bs] * ILOSC;
                    *(floatx4*)&red[((wq * 64 + bs * 16 + m) * 36 + cs * 16 + qq * 4)] = v;
                }
            __syncthreads();
            if (eact) {
                _Float16* o = w.h0 + (size_t)(t & 1) * HSLOT;
                float hn4[4];
#pragma unroll
                for (int u = 0; u < 4; ++u) {
                    const int jl = equad * 4 + u;
                    floatx4 g = *(floatx4*)&red[(0 * 64 + eb) * 36 + jl * 4];
#pragma unroll
                    for (int q2 = 1; q2 < 4; ++q2)
                        g += *(floatx4*)&red[((q2 * 64 + eb) * 36 + jl * 4)];
                    const int j = j0g + jl;
                    float ig = fsig (g.x + b0[0 * H + j]);
                    float fg = fsig (g.y + b0[1 * H + j]);
                    float gg = ftanh(g.z + b0[2 * H + j]);
                    float og = fsig (g.w + b0[3 * H + j]);
                    float cn = fg * c0r[u] + ig * gg;
                    float hn = og * ftanh(cn);
                    c0r[u] = cn;
                    hn4[u] = hn;
                }
                union { _Float16 h[4]; u64 uu; } ph, pl;
#pragma unroll
                for (int u = 0; u < 4; ++u) {
                    _Float16 hh = (_Float16)hn4[u];
                    ph.h[u] = hh;
                    pl.h[u] = (_Float16)((hn4[u] - (float)hh) * LOSC);
                }
                _Float16* rec = o + ((size_t)bg_e * (H/8) + cblk) * 16 + equad * 4;
                st_u64_cc(rec,     ph.uu);
                st_u64_cc(rec + 8, pl.uu);
            }
            __syncthreads();
        }

        // ================= phase L1(t-1): g = W1 * [h0(t-1); h1(t-2)] =================
        if (t >= 1) {
            const int tt = t - 1;
            floatx4 acc0[8], acc1[8];
#pragma unroll
            for (int i = 0; i < 8; ++i) {
                floatx4 z = {0.f, 0.f, 0.f, 0.f};
                acc0[i] = z; acc1[i] = z;
            }
            half8 Bh[2][4], Bl[2][4];
            const _Float16* y0 = w.h0 + (size_t)(tt & 1) * HSLOT;
            const _Float16* y1 = w.h1 + (size_t)((tt + 1) & 1) * HSLOT;
            {
                const int ch = (wq * 32 + qq * 8) >> 3;   // kb = wq < 16 -> y0
#pragma unroll
                for (int bs = 0; bs < 4; ++bs) {
                    const _Float16* bp = y0 + ((size_t)(b0gl + bs * 16 + m) * (H/8) + ch) * 16;
                    Bh[0][bs] = ld_h8_cc(bp);
                    Bl[0][bs] = ld_h8_cc(bp + 8);
                }
            }
#pragma unroll
            for (int i = 0; i < 8; ++i) {
                const int cur = i & 1;
                if (i + 1 < 8) {
                    const int kbn = wq + 4 * (i + 1);
                    const int kon = kbn * 32 + qq * 8;
                    const _Float16* sx = (kbn < 16) ? y0 : y1;
                    const int ch = ((kbn < 16) ? kon : kon - 512) >> 3;
#pragma unroll
                    for (int bs = 0; bs < 4; ++bs) {
                        const _Float16* bp = sx + ((size_t)(b0gl + bs * 16 + m) * (H/8) + ch) * 16;
                        Bh[cur ^ 1][bs] = ld_h8_cc(bp);
                        Bl[cur ^ 1][bs] = ld_h8_cc(bp + 8);
                    }
                }
#pragma unroll
                for (int cs = 0; cs < 2; ++cs)
#pragma unroll
                    for (int bs = 0; bs < 4; ++bs) {
                        const int ti = cs * 4 + bs;
                        acc0[ti] = __builtin_amdgcn_mfma_f32_16x16x32_f16(W1hr[i][cs], Bh[cur][bs], acc0[ti], 0, 0, 0);
                        acc1[ti] = __builtin_amdgcn_mfma_f32_16x16x32_f16(W1hr[i][cs], Bl[cur][bs], acc1[ti], 0, 0, 0);
                        acc1[ti] = __builtin_amdgcn_mfma_f32_16x16x32_f16(W1lr[i][cs], Bh[cur][bs], acc1[ti], 0, 0, 0);
                    }
            }
#pragma unroll
            for (int cs = 0; cs < 2; ++cs)
#pragma unroll
                for (int bs = 0; bs < 4; ++bs) {
                    floatx4 v = acc0[cs * 4 + bs] + acc1[cs * 4 + bs] * ILOSC;
                    *(floatx4*)&red[((wq * 64 + bs * 16 + m) * 36 + cs * 16 + qq * 4)] = v;
                }
            __syncthreads();
            if (eact) {
                _Float16* o = w.h1 + (size_t)(tt & 1) * HSLOT;
                float hn4[4];
#pragma unroll
                for (int u = 0; u < 4; ++u) {
                    const int jl = equad * 4 + u;
                    floatx4 g = *(floatx4*)&red[(0 * 64 + eb) * 36 + jl * 4];
#pragma unroll
                    for (int q2 = 1; q2 < 4; ++q2)
                        g += *(floatx4*)&red[((q2 * 64 + eb) * 36 + jl * 4)];
                    const int j = j0g + jl;
                    float ig = fsig (g.x + b1[0 * H + j]);
                    float fg = fsig (g.y + b1[1 * H + j]);
                    float gg = ftanh(g.z + b1[2 * H + j]);
                    float og = fsig (g.w + b1[3 * H + j]);
                    float cn = fg * c1r[u] + ig * gg;
                    float hn = og * ftanh(cn);
                    c1r[u] = cn;
                    hn4[u] = hn;
                }
                if (tt <= lastb) {
#pragma unroll
                    for (int u = 0; u < 4; ++u) hmr[u] = fmaxf(hmr[u], hn4[u]);
                }
                union { _Float16 h[4]; u64 uu; } ph, pl;
#pragma unroll
                for (int u = 0; u < 4; ++u) {
                    _Float16 hh = (_Float16)hn4[u];
                    ph.h[u] = hh;
                    pl.h[u] = (_Float16)((hn4[u] - (float)hh) * LOSC);
                }
                _Float16* rec = o + ((size_t)bg_e * (H/8) + cblk) * 16 + equad * 4;
                st_u64_cc(rec,     ph.uu);
                st_u64_cc(rec + 8, pl.uu);
            }
            __syncthreads();
        }

        // ================= grid barrier (r3-proven flag scheme) =================
        if (t < T) {
            const unsigned tgt = (unsigned)(t + 1);
            asm volatile("s_waitcnt vmcnt(0)" ::: "memory");
            __syncthreads();
            if (tid == 0)
                __hip_atomic_store(&w.arr[bid], tgt, __ATOMIC_RELAXED, __HIP_MEMORY_SCOPE_AGENT);
            if (bid == 0) {
                if (tid < 64) {
                    for (;;) {
                        unsigned f0 = __hip_atomic_load(&w.arr[tid],       __ATOMIC_RELAXED, __HIP_MEMORY_SCOPE_AGENT);
                        unsigned f1 = __hip_atomic_load(&w.arr[tid + 64],  __ATOMIC_RELAXED, __HIP_MEMORY_SCOPE_AGENT);
                        unsigned f2 = __hip_atomic_load(&w.arr[tid + 128], __ATOMIC_RELAXED, __HIP_MEMORY_SCOPE_AGENT);
                        unsigned f3 = __hip_atomic_load(&w.arr[tid + 192], __ATOMIC_RELAXED, __HIP_MEMORY_SCOPE_AGENT);
                        bool ok = (f0 >= tgt) & (f1 >= tgt) & (f2 >= tgt) & (f3 >= tgt);
                        if (__all(ok)) break;
                        __builtin_amdgcn_s_sleep(2);
                    }
                    if (tid == 0)
                        __hip_atomic_store(w.gen, tgt, __ATOMIC_RELAXED, __HIP_MEMORY_SCOPE_AGENT);
                }
            } else {
                if (tid == 0) {
                    while (__hip_atomic_load(w.gen, __ATOMIC_RELAXED, __HIP_MEMORY_SCOPE_AGENT) < tgt)
                        __builtin_amdgcn_s_sleep(4);
                }
            }
            __syncthreads();
            asm volatile("" ::: "memory");
        }
    }

    // ---- write out register-resident maxpool state ----
    if (eact)
        *(float4*)(w.hmax + (size_t)bg_e * H + j0g + equad * 4) =
            make_float4(hmr[0], hmr[1], hmr[2], hmr[3]);
}

// ---------------- final: logits ----------------
__global__ __launch_bounds__(64) void k_out(const float* __restrict__ hmax,
                                            const float* __restrict__ Wout,
                                            const float* __restrict__ bout,
                                            float* __restrict__ out) {
    const int b = blockIdx.x * 64 + threadIdx.x;
    float a[NC] = {0.f, 0.f, 0.f, 0.f, 0.f};
    const float* hm = hmax + (size_t)b * H;
    for (int j = 0; j < H; ++j) {
        float hv = hm[j];
#pragma unroll
        for (int cls = 0; cls < NC; ++cls)
            a[cls] = fmaf(hv, Wout[cls * H + j], a[cls]);
    }
#pragma unroll
    for (int cls = 0; cls < NC; ++cls)
        out[b * NC + cls] = a[cls] + bout[cls];
}

// ---------------- launch ----------------
extern "C" void kernel_launch(void* const* d_in, const int* in_sizes, int n_in,
                              void* d_out, int out_size, void* d_ws, size_t ws_size,
                              hipStream_t stream) {
    const int*   X    = (const int*)  d_in[0];
    const float* emb  = (const float*)d_in[1];
    const float* Wih0 = (const float*)d_in[2];
    const float* Whh0 = (const float*)d_in[3];
    const float* b0   = (const float*)d_in[4];
    const float* Wih1 = (const float*)d_in[5];
    const float* Whh1 = (const float*)d_in[6];
    const float* b1   = (const float*)d_in[7];
    const float* Wout = (const float*)d_in[8];
    const float* bout = (const float*)d_in[9];
    float* out = (float*)d_out;
    char* ws = (char*)d_ws;
    WS w = wsmap(ws);

    k_prep<<<(NW0 + NW1 + 255) / 256, 256, 0, stream>>>(Wih0, Whh0, Wih1, Whh1, ws);
    k_init<<<2048, 256, 0, stream>>>(X, ws);

    {
        void* args[] = {(void*)&X, (void*)&emb, (void*)&b0, (void*)&b1, (void*)&ws};
        hipError_t e = hipLaunchCooperativeKernel((const void*)k_lstm, dim3(NBLK), dim3(256),
                                                  args, 0, stream);
        if (e != hipSuccess) {
            // 256 blocks at 1/CU with nothing else resident: co-residency holds.
            k_lstm<<<NBLK, 256, 0, stream>>>(X, emb, b0, b1, ws);
        }
    }

    k_out<<<4, 64, 0, stream>>>(w.hmax, Wout, bout, out);
}